// Round 5
// baseline (912.616 us; speedup 1.0000x reference)
//
#include <hip/hip_runtime.h>
#include <math.h>

#define NN 50000
#define NE 600000
#define HID 128
#define NCLS 10
#define BK 16

// ================= graph prep: CSR by destination =================

__global__ __launch_bounds__(256) void k_count(const int* __restrict__ edge,
                                               int* __restrict__ counts) {
    int e = blockIdx.x * 256 + threadIdx.x;
    if (e < NE) atomicAdd(&counts[edge[NE + e]], 1);
}

__device__ __forceinline__ int wave_incl_scan(int x, int lane) {
#pragma unroll
    for (int off = 1; off < 64; off <<= 1) {
        int y = __shfl_up(x, off, 64);
        if (lane >= off) x += y;
    }
    return x;
}

__global__ __launch_bounds__(256) void k_scan1(const int* __restrict__ counts,
                                               int* __restrict__ rowptr,
                                               int* __restrict__ bsum,
                                               float* __restrict__ dinv) {
    __shared__ int ws[4];
    int tid = threadIdx.x;
    int i = blockIdx.x * 256 + tid;
    int lane = tid & 63, wv = tid >> 6;
    int v = (i < NN) ? counts[i] : 0;
    if (i < NN) dinv[i] = rsqrtf((float)(v + 1));
    int x = wave_incl_scan(v, lane);
    if (lane == 63) ws[wv] = x;
    __syncthreads();
    int off = 0;
    for (int j = 0; j < wv; ++j) off += ws[j];
    if (i < NN) rowptr[i] = off + x - v;
    if (tid == 255) bsum[blockIdx.x] = off + x;
}

__global__ __launch_bounds__(256) void k_scan2(int* __restrict__ bsum, int n) {
    __shared__ int ws[4];
    int tid = threadIdx.x;
    int lane = tid & 63, wv = tid >> 6;
    int v = (tid < n) ? bsum[tid] : 0;
    int x = wave_incl_scan(v, lane);
    if (lane == 63) ws[wv] = x;
    __syncthreads();
    int off = 0;
    for (int j = 0; j < wv; ++j) off += ws[j];
    __syncthreads();
    if (tid < n) bsum[tid] = off + x - v;
}

__global__ __launch_bounds__(256) void k_scan3(int* __restrict__ rowptr,
                                               const int* __restrict__ bsum) {
    int i = blockIdx.x * 256 + threadIdx.x;
    if (i < NN) rowptr[i] += bsum[blockIdx.x];
    if (i == 0) rowptr[NN] = NE;
}

__global__ __launch_bounds__(256) void k_fill(const int* __restrict__ edge,
                                              const int* __restrict__ rowptr,
                                              int* __restrict__ cursor,
                                              const float* __restrict__ dinv,
                                              int2* __restrict__ csr) {
    int e = blockIdx.x * 256 + threadIdx.x;
    if (e >= NE) return;
    int s = edge[e], d = edge[NE + e];
    int p = rowptr[d] + atomicAdd(&cursor[d], 1);
    csr[p] = make_int2(s, __float_as_int(dinv[s] * dinv[d]));
}

// ========== dense: H[N,128] @ W[128,128] -> T ==========
// 128x128 tile, 256 thr, 8x8/thread; BK=16 double-buffered LDS, one barrier
// per k-tile, next tile's global loads issued before the barrier so they
// retire behind the 16x64-FMA compute block.

__global__ __launch_bounds__(256) void k_matmul128(const float* __restrict__ H,
                                                   const float* __restrict__ W,
                                                   float* __restrict__ T) {
    __shared__ float As[2][BK * 128];  // k-major [k][row], 8 KB each
    __shared__ float Bs[2][BK * 128];  // [k][col]
    int tid = threadIdx.x;
    int lane = tid & 63, w = tid >> 6;
    int wr = lane >> 3, wc = lane & 7;
    int wy = w >> 1, wx = w & 1;
    int lr0 = wy * 64 + wr * 8;
    int lc0 = wx * 64 + wc * 8;
    int rowBase = blockIdx.x * 128;

    int sa_row = tid >> 1;         // 0..127
    int sa_k = (tid & 1) * 8;      // 0 or 8
    int sa_grow = rowBase + sa_row;
    if (sa_grow >= NN) sa_grow = NN - 1;
    const float* hbase = H + (size_t)sa_grow * HID + sa_k;

    float acc[8][8];
#pragma unroll
    for (int i = 0; i < 8; ++i)
#pragma unroll
        for (int j = 0; j < 8; ++j) acc[i][j] = 0.f;

    // prologue: tile 0 -> buf 0
    {
        float4 a0 = ((const float4*)hbase)[0];
        float4 a1 = ((const float4*)hbase)[1];
        const float4* wsrc = (const float4*)W;
        float4 b0 = wsrc[tid], b1 = wsrc[tid + 256];
        As[0][(sa_k + 0) * 128 + sa_row] = a0.x; As[0][(sa_k + 1) * 128 + sa_row] = a0.y;
        As[0][(sa_k + 2) * 128 + sa_row] = a0.z; As[0][(sa_k + 3) * 128 + sa_row] = a0.w;
        As[0][(sa_k + 4) * 128 + sa_row] = a1.x; As[0][(sa_k + 5) * 128 + sa_row] = a1.y;
        As[0][(sa_k + 6) * 128 + sa_row] = a1.z; As[0][(sa_k + 7) * 128 + sa_row] = a1.w;
        ((float4*)Bs[0])[tid] = b0;
        ((float4*)Bs[0])[tid + 256] = b1;
    }

    for (int t = 0; t < 8; ++t) {
        int cur = t & 1;
        float4 na0, na1, nb0, nb1;
        if (t < 7) {  // issue next tile's global loads now; used after compute
            const float4* hn = (const float4*)(hbase + (t + 1) * BK);
            na0 = hn[0]; na1 = hn[1];
            const float4* wn = (const float4*)(W + (size_t)(t + 1) * BK * HID);
            nb0 = wn[tid]; nb1 = wn[tid + 256];
        }
        __syncthreads();  // buf[cur] stores visible; buf[1-cur] readers (t-1) done
#pragma unroll
        for (int kk = 0; kk < BK; ++kk) {
            float a[8], b[8];
            ((float4*)a)[0] = *(const float4*)&As[cur][kk * 128 + lr0];
            ((float4*)a)[1] = *(const float4*)&As[cur][kk * 128 + lr0 + 4];
            ((float4*)b)[0] = *(const float4*)&Bs[cur][kk * 128 + lc0];
            ((float4*)b)[1] = *(const float4*)&Bs[cur][kk * 128 + lc0 + 4];
#pragma unroll
            for (int i = 0; i < 8; ++i)
#pragma unroll
                for (int j = 0; j < 8; ++j) acc[i][j] += a[i] * b[j];
        }
        if (t < 7) {
            int nxt = 1 - cur;
            As[nxt][(sa_k + 0) * 128 + sa_row] = na0.x; As[nxt][(sa_k + 1) * 128 + sa_row] = na0.y;
            As[nxt][(sa_k + 2) * 128 + sa_row] = na0.z; As[nxt][(sa_k + 3) * 128 + sa_row] = na0.w;
            As[nxt][(sa_k + 4) * 128 + sa_row] = na1.x; As[nxt][(sa_k + 5) * 128 + sa_row] = na1.y;
            As[nxt][(sa_k + 6) * 128 + sa_row] = na1.z; As[nxt][(sa_k + 7) * 128 + sa_row] = na1.w;
            ((float4*)Bs[nxt])[tid] = nb0;
            ((float4*)Bs[nxt])[tid + 256] = nb1;
        }
    }
#pragma unroll
    for (int i = 0; i < 8; ++i) {
        int gr = rowBase + lr0 + i;
        if (gr < NN) {
            float4 o0 = {acc[i][0], acc[i][1], acc[i][2], acc[i][3]};
            float4 o1 = {acc[i][4], acc[i][5], acc[i][6], acc[i][7]};
            float4* dst = (float4*)(T + (size_t)gr * HID + lc0);
            dst[0] = o0;
            dst[1] = o1;
        }
    }
}

// ============ sparse by gather: one wave per node, pipelined, fused epilogue ============
// 4 edge slots x 16 lanes; lane covers float4 indices c16 and c16+16 so each
// load/store instruction touches 256 CONTIGUOUS bytes (full 64-B lines).

__global__ __launch_bounds__(256) void k_gather_agg(const float* __restrict__ T,
                                                    float* __restrict__ Hout,
                                                    const int* __restrict__ rowptr,
                                                    const int2* __restrict__ csr,
                                                    const float* __restrict__ dinv,
                                                    const float* __restrict__ bias) {
    int lane = threadIdx.x & 63;
    int node = (blockIdx.x * 256 + threadIdx.x) >> 6;
    if (node >= NN) return;
    int slot = lane >> 4, c16 = lane & 15;

    int beg = rowptr[node], end = rowptr[node + 1];
    float4 acc0 = {0.f, 0.f, 0.f, 0.f}, acc1 = {0.f, 0.f, 0.f, 0.f};
    const int2 zed = make_int2(0, 0);  // norm bits 0 -> weight 0

    int i = beg + slot;
    int2 e0 = (i < end) ? csr[i] : zed;
    int2 e1 = (i + 4 < end) ? csr[i + 4] : zed;
    for (; i < end; i += 8) {
        int2 p0 = (i + 8 < end) ? csr[i + 8] : zed;
        int2 p1 = (i + 12 < end) ? csr[i + 12] : zed;
        const float4* s0 = (const float4*)(T + (size_t)e0.x * HID);
        const float4* s1 = (const float4*)(T + (size_t)e1.x * HID);
        float4 u0 = s0[c16], u1 = s0[c16 + 16];
        float4 v0 = s1[c16], v1 = s1[c16 + 16];
        float w0 = __int_as_float(e0.y);
        float w1 = __int_as_float(e1.y);
        acc0.x += w0 * u0.x; acc0.y += w0 * u0.y; acc0.z += w0 * u0.z; acc0.w += w0 * u0.w;
        acc1.x += w0 * u1.x; acc1.y += w0 * u1.y; acc1.z += w0 * u1.z; acc1.w += w0 * u1.w;
        acc0.x += w1 * v0.x; acc0.y += w1 * v0.y; acc0.z += w1 * v0.z; acc0.w += w1 * v0.w;
        acc1.x += w1 * v1.x; acc1.y += w1 * v1.y; acc1.z += w1 * v1.z; acc1.w += w1 * v1.w;
        e0 = p0; e1 = p1;
    }
    acc0.x += __shfl_xor(acc0.x, 16, 64); acc0.y += __shfl_xor(acc0.y, 16, 64);
    acc0.z += __shfl_xor(acc0.z, 16, 64); acc0.w += __shfl_xor(acc0.w, 16, 64);
    acc1.x += __shfl_xor(acc1.x, 16, 64); acc1.y += __shfl_xor(acc1.y, 16, 64);
    acc1.z += __shfl_xor(acc1.z, 16, 64); acc1.w += __shfl_xor(acc1.w, 16, 64);
    acc0.x += __shfl_xor(acc0.x, 32, 64); acc0.y += __shfl_xor(acc0.y, 32, 64);
    acc0.z += __shfl_xor(acc0.z, 32, 64); acc0.w += __shfl_xor(acc0.w, 32, 64);
    acc1.x += __shfl_xor(acc1.x, 32, 64); acc1.y += __shfl_xor(acc1.y, 32, 64);
    acc1.z += __shfl_xor(acc1.z, 32, 64); acc1.w += __shfl_xor(acc1.w, 32, 64);

    if (slot == 0) {
        float sn = dinv[node];
        sn *= sn;
        const float4* trow = (const float4*)(T + (size_t)node * HID);
        float4 t0 = trow[c16], t1 = trow[c16 + 16];
        const float4* b4 = (const float4*)bias;
        float4 b0 = b4[c16], b1 = b4[c16 + 16];
        float4 r0, r1;
        r0.x = acc0.x + sn * t0.x + b0.x; r0.y = acc0.y + sn * t0.y + b0.y;
        r0.z = acc0.z + sn * t0.z + b0.z; r0.w = acc0.w + sn * t0.w + b0.w;
        r1.x = acc1.x + sn * t1.x + b1.x; r1.y = acc1.y + sn * t1.y + b1.y;
        r1.z = acc1.z + sn * t1.z + b1.z; r1.w = acc1.w + sn * t1.w + b1.w;
        r0.x = r0.x > 0.f ? r0.x : expm1f(r0.x);
        r0.y = r0.y > 0.f ? r0.y : expm1f(r0.y);
        r0.z = r0.z > 0.f ? r0.z : expm1f(r0.z);
        r0.w = r0.w > 0.f ? r0.w : expm1f(r0.w);
        r1.x = r1.x > 0.f ? r1.x : expm1f(r1.x);
        r1.y = r1.y > 0.f ? r1.y : expm1f(r1.y);
        r1.z = r1.z > 0.f ? r1.z : expm1f(r1.z);
        r1.w = r1.w > 0.f ? r1.w : expm1f(r1.w);
        float4* dst = (float4*)(Hout + (size_t)node * HID);
        dst[c16] = r0;
        dst[c16 + 16] = r1;
    }
}

// ================= output layer (128 -> 10) =================

__global__ __launch_bounds__(256) void k_matmul_out(const float* __restrict__ H,
                                                    const float* __restrict__ W,
                                                    float* __restrict__ T2) {
    __shared__ float Ws[128 * 11];
    int tid = threadIdx.x;
    for (int m = tid; m < HID * NCLS; m += 256) {
        int k = m / NCLS, c = m - k * NCLS;
        Ws[k * 11 + c] = W[m];
    }
    __syncthreads();
    int row = (blockIdx.x * 256 + tid) >> 4;
    int c16 = tid & 15;
    if (row >= NN) return;
    const float* h = H + (size_t)row * HID;
    float acc[NCLS];
#pragma unroll
    for (int c = 0; c < NCLS; ++c) acc[c] = 0.f;
#pragma unroll
    for (int j = 0; j < 8; ++j) {
        float hv = h[c16 + 16 * j];
        const float* wr = &Ws[(c16 + 16 * j) * 11];
#pragma unroll
        for (int c = 0; c < NCLS; ++c) acc[c] += hv * wr[c];
    }
#pragma unroll
    for (int off = 8; off >= 1; off >>= 1) {
#pragma unroll
        for (int c = 0; c < NCLS; ++c) acc[c] += __shfl_xor(acc[c], off, 16);
    }
    if (c16 < NCLS) T2[(size_t)row * NCLS + c16] = acc[c16];
}

__global__ __launch_bounds__(256) void k_gather_out(const float* __restrict__ T2,
                                                    float* __restrict__ out,
                                                    const int* __restrict__ rowptr,
                                                    const int2* __restrict__ csr,
                                                    const float* __restrict__ dinv,
                                                    const float* __restrict__ bias) {
    int lane = threadIdx.x & 63;
    int node = (blockIdx.x * 256 + threadIdx.x) >> 6;
    if (node >= NN) return;
    int slot = lane >> 4, c = lane & 15;
    int beg = rowptr[node], end = rowptr[node + 1];
    float acc = 0.f;
    if (c < NCLS) {
        for (int i = beg + slot; i < end; i += 4) {
            int2 e = csr[i];
            acc += __int_as_float(e.y) * T2[(size_t)e.x * NCLS + c];
        }
    }
    acc += __shfl_xor(acc, 16, 64);
    acc += __shfl_xor(acc, 32, 64);
    if (slot == 0 && c < NCLS) {
        float sn = dinv[node];
        sn *= sn;
        out[node * NCLS + c] = acc + sn * T2[(size_t)node * NCLS + c] + bias[c];
    }
}

// ================= launch =================

extern "C" void kernel_launch(void* const* d_in, const int* in_sizes, int n_in,
                              void* d_out, int out_size, void* d_ws, size_t ws_size,
                              hipStream_t stream) {
    (void)in_sizes; (void)n_in; (void)out_size; (void)ws_size;
    const float* x       = (const float*)d_in[0];
    const int*   edge    = (const int*)d_in[1];   // [2, NE] int32
    const float* W_stack = (const float*)d_in[2];
    const float* b_stack = (const float*)d_in[3];
    const float* W_out   = (const float*)d_in[4];
    const float* b_out   = (const float*)d_in[5];
    float* out = (float*)d_out;

    char* ws = (char*)d_ws;
    const size_t bigbuf = (size_t)NN * HID * sizeof(float);  // 25.6 MB
    float* X      = (float*)ws;
    float* Y      = (float*)(ws + bigbuf);
    char*  p      = ws + 2 * bigbuf;
    int2*  csr    = (int2*)p;              p += sizeof(int2) * NE;
    float* dinv   = (float*)p;             p += sizeof(float) * NN;
    int*   rowptr = (int*)p;               p += sizeof(int) * (NN + 1);
    int*   counts = (int*)p;               p += sizeof(int) * NN;    // reused as cursor
    int*   bsum   = (int*)p;               p += sizeof(int) * 256;

    const int NB_N  = (NN + 255) / 256;        // 196
    const int NB_E  = (NE + 255) / 256;
    const int NB_MM = (NN + 127) / 128;        // 391
    const int NB_W  = (NN * 64 + 255) / 256;   // one wave per node
    const int NB_O  = (NN * 16 + 255) / 256;

    // ---- CSR build (per call) ----
    hipMemsetAsync(counts, 0, sizeof(int) * NN, stream);
    k_count<<<NB_E, 256, 0, stream>>>(edge, counts);
    k_scan1<<<NB_N, 256, 0, stream>>>(counts, rowptr, bsum, dinv);
    k_scan2<<<1, 256, 0, stream>>>(bsum, NB_N);
    k_scan3<<<NB_N, 256, 0, stream>>>(rowptr, bsum);
    hipMemsetAsync(counts, 0, sizeof(int) * NN, stream);  // reuse as cursor
    k_fill<<<NB_E, 256, 0, stream>>>(edge, rowptr, counts, dinv, csr);

    // ---- 8 hidden layers ----
    const float* Hin = x;
    for (int l = 0; l < 8; ++l) {
        k_matmul128<<<NB_MM, 256, 0, stream>>>(Hin, W_stack + (size_t)l * HID * HID, Y);
        k_gather_agg<<<NB_W, 256, 0, stream>>>(Y, X, rowptr, csr, dinv,
                                               b_stack + (size_t)l * HID);
        Hin = X;
    }

    // ---- output layer ----
    k_matmul_out<<<NB_O, 256, 0, stream>>>(X, W_out, Y);
    k_gather_out<<<NB_W, 256, 0, stream>>>(Y, out, rowptr, csr, dinv, b_out);
}